// Round 7
// baseline (7998.232 us; speedup 1.0000x reference)
//
#include <hip/hip_runtime.h>
#include <hip/hip_bf16.h>
#include <cstdint>
#include <cstddef>

#define HID       1152
#define D_INNER   2304
#define D_STATE   64
#define HEADDIM   64
#define NHEADS    36
#define CHUNKX    64
#define D_CONV    4
#define CONV_DIMX 2432          /* D_INNER + 2*D_STATE */
#define D_IN_PROJ 4772          /* 2*D_INNER + 2*D_STATE + NHEADS */
#define BATCH     4
#define SEQLEN    4096
#define NCHUNK    64            /* SEQLEN / CHUNKX */
#define EPSF      1e-5f
#define LD        65            /* padded LDS leading dim: conflict-free */

// bf16 <-> f32 via raw bits (RNE)
__device__ __forceinline__ unsigned short f2bb(float f) {
    unsigned u = __float_as_uint(f);
    unsigned r = (u + 0x7FFFu + ((u >> 16) & 1u)) >> 16;
    return (unsigned short)r;
}
__device__ __forceinline__ float b2ff(unsigned short s) {
    return __uint_as_float(((unsigned)s) << 16);
}
__device__ __forceinline__ float4 bu4_to_f4(ushort4 v) {
    return make_float4(b2ff(v.x), b2ff(v.y), b2ff(v.z), b2ff(v.w));
}
__device__ __forceinline__ float siluf(float a) {
    return a / (1.f + expf(-a));
}

// ---------------------------------------------------------------------------
// GEMM1: zxbcdt = u @ in_proj_w.T ; unchanged (audited 5x)
// ---------------------------------------------------------------------------
__global__ __launch_bounds__(256) void k_gemm_inproj(
    const float* __restrict__ U, const float* __restrict__ W,
    unsigned short* __restrict__ z, unsigned short* __restrict__ xbc,
    float* __restrict__ dtr)
{
    __shared__ float As[16][64];
    __shared__ float Bs[16][64];
    const int K = HID;
    int tid = threadIdx.x;
    int bm = blockIdx.x, bn = blockIdx.y;
    int tx = tid & 15, ty = tid >> 4;
    int lrow = tid >> 2;
    int lk   = (tid & 3) << 2;
    const float* aptr = U + (size_t)(bm * 64 + lrow) * K + lk;
    int brow = bn * 64 + lrow;
    const float* bptr = W + (size_t)brow * K + lk;
    bool bok = brow < D_IN_PROJ;
    float acc[4][4];
#pragma unroll
    for (int i = 0; i < 4; ++i)
#pragma unroll
        for (int j = 0; j < 4; ++j) acc[i][j] = 0.f;

    for (int k0 = 0; k0 < K; k0 += 16) {
        float4 av = *(const float4*)(aptr + k0);
        float4 bv = bok ? *(const float4*)(bptr + k0) : make_float4(0.f, 0.f, 0.f, 0.f);
        __syncthreads();
        As[lk + 0][lrow] = av.x; As[lk + 1][lrow] = av.y;
        As[lk + 2][lrow] = av.z; As[lk + 3][lrow] = av.w;
        Bs[lk + 0][lrow] = bv.x; Bs[lk + 1][lrow] = bv.y;
        Bs[lk + 2][lrow] = bv.z; Bs[lk + 3][lrow] = bv.w;
        __syncthreads();
#pragma unroll
        for (int kk = 0; kk < 16; ++kk) {
            float4 a4 = *(const float4*)&As[kk][ty << 2];
            float4 b4 = *(const float4*)&Bs[kk][tx << 2];
            float a[4] = {a4.x, a4.y, a4.z, a4.w};
            float b[4] = {b4.x, b4.y, b4.z, b4.w};
#pragma unroll
            for (int i = 0; i < 4; ++i)
#pragma unroll
                for (int j = 0; j < 4; ++j) acc[i][j] = fmaf(a[i], b[j], acc[i][j]);
        }
    }
    int m0 = bm * 64 + (ty << 2);
    int n0 = bn * 64 + (tx << 2);
#pragma unroll
    for (int i = 0; i < 4; ++i) {
        size_t m = m0 + i;
#pragma unroll
        for (int j = 0; j < 4; ++j) {
            int n = n0 + j;
            if (n >= D_IN_PROJ) continue;
            float v = acc[i][j];
            if (n < D_INNER)                  z[m * D_INNER + n] = f2bb(v);
            else if (n < D_INNER + CONV_DIMX) xbc[m * CONV_DIMX + (n - D_INNER)] = f2bb(v);
            else                              dtr[m * NHEADS + (n - D_INNER - CONV_DIMX)] = v;
        }
    }
}

// ---------------------------------------------------------------------------
// Depthwise causal conv (width 4, left zero-pad per batch) + silu. Trivial.
// ---------------------------------------------------------------------------
__global__ __launch_bounds__(256) void k_conv(
    const unsigned short* __restrict__ xin, const float* __restrict__ cw,
    const float* __restrict__ cb, unsigned short* __restrict__ xout)
{
    int c = blockIdx.x * 256 + threadIdx.x;
    if (c >= CONV_DIMX) return;
    int t = blockIdx.y;
    int bz = blockIdx.z;
    const unsigned short* base = xin + ((size_t)bz * SEQLEN) * CONV_DIMX + c;
    float acc = cb[c];
#pragma unroll
    for (int j = 0; j < 4; ++j) {
        int tt = t - 3 + j;
        if (tt >= 0) acc = fmaf(b2ff(base[(size_t)tt * CONV_DIMX]), cw[c * 4 + j], acc);
    }
    xout[((size_t)bz * SEQLEN + t) * CONV_DIMX + c] = f2bb(siluf(acc));
}

// ---------------------------------------------------------------------------
// dt = softplus(dt_raw + dt_bias) (in-place); adt = -exp(A_log)*dt
// ---------------------------------------------------------------------------
__global__ __launch_bounds__(256) void k_dt(
    float* __restrict__ dtio, float* __restrict__ adt,
    const float* __restrict__ dt_bias, const float* __restrict__ A_log, int n)
{
    int i = blockIdx.x * 256 + threadIdx.x;
    if (i >= n) return;
    int h = i % NHEADS;
    float x = dtio[i] + dt_bias[h];
    float sp = (x > 20.f) ? x : log1pf(expf(x));
    dtio[i] = sp;
    adt[i] = -expf(A_log[h]) * sp;
}

// ---------------------------------------------------------------------------
// Sequential SSM recurrence:
//   h_l = exp(adt_l) * h_{l-1} + (dt_l * x_l) outer B_l
//   y_l = C_l . h_l + D * x_l
// One block per (head, local-batch); 64-step LDS tiles; state in registers.
// ---------------------------------------------------------------------------
__global__ __launch_bounds__(256) void k_ssm(
    const unsigned short* __restrict__ xc, const float* __restrict__ dtp,
    const float* __restrict__ adt, const float* __restrict__ Dp,
    unsigned short* __restrict__ y)
{
    __shared__ float Xs[CHUNKX * LD];   // [l][p]
    __shared__ float Bs[CHUNKX * LD];   // [l][n]
    __shared__ float Cs[CHUNKX * LD];   // [l][n]
    __shared__ float dts_sh[CHUNKX];
    __shared__ float adts_sh[CHUNKX];
    int h = blockIdx.x, bz = blockIdx.y;
    int tid = threadIdx.x;
    int p = tid >> 2;
    int q = tid & 3;
    float Dval = Dp[h];

    float S[16];
#pragma unroll
    for (int i = 0; i < 16; ++i) S[i] = 0.f;

    for (int tile = 0; tile < NCHUNK; ++tile) {
        size_t row0 = (size_t)bz * SEQLEN + (size_t)tile * CHUNKX;
        if (tid < CHUNKX) {
            dts_sh[tid]  = dtp[(row0 + tid) * NHEADS + h];
            adts_sh[tid] = adt[(row0 + tid) * NHEADS + h];
        }
#pragma unroll
        for (int it = 0; it < 4; ++it) {
            int idx = tid + it * 256;
            int r = idx >> 4;
            int c4 = (idx & 15) << 2;
            const unsigned short* gp = xc + (row0 + r) * CONV_DIMX;
            float4 xv = bu4_to_f4(*(const ushort4*)(gp + h * HEADDIM + c4));
            float* xd = &Xs[r * LD + c4];
            xd[0] = xv.x; xd[1] = xv.y; xd[2] = xv.z; xd[3] = xv.w;
            float4 bv = bu4_to_f4(*(const ushort4*)(gp + D_INNER + c4));
            float* bd = &Bs[r * LD + c4];
            bd[0] = bv.x; bd[1] = bv.y; bd[2] = bv.z; bd[3] = bv.w;
            float4 cv = bu4_to_f4(*(const ushort4*)(gp + D_INNER + D_STATE + c4));
            float* cd = &Cs[r * LD + c4];
            cd[0] = cv.x; cd[1] = cv.y; cd[2] = cv.z; cd[3] = cv.w;
        }
        __syncthreads();

        for (int l = 0; l < CHUNKX; ++l) {
            float el = expf(adts_sh[l]);
            float xl = Xs[l * LD + p];
            float xd = xl * dts_sh[l];
            const float* bl = &Bs[l * LD + (q << 4)];
            const float* cl = &Cs[l * LD + (q << 4)];
            float yp = 0.f;
#pragma unroll
            for (int i = 0; i < 16; ++i) {
                S[i] = fmaf(el, S[i], xd * bl[i]);
                yp = fmaf(cl[i], S[i], yp);
            }
            yp += __shfl_xor(yp, 1, 64);
            yp += __shfl_xor(yp, 2, 64);
            if (q == 0)
                y[(row0 + l) * (size_t)D_INNER + h * HEADDIM + p] =
                    f2bb(fmaf(Dval, xl, yp));
        }
        __syncthreads();
    }
}

// ---------------------------------------------------------------------------
// Gated RMSNorm, in place on y (bf16)
// ---------------------------------------------------------------------------
__global__ __launch_bounds__(256) void k_norm(
    unsigned short* __restrict__ y, const unsigned short* __restrict__ z,
    const float* __restrict__ nw)
{
    int row = blockIdx.x;
    int tid = threadIdx.x;
    unsigned short* yp = y + (size_t)row * D_INNER;
    const unsigned short* zp = z + (size_t)row * D_INNER;
    float vals[9];
    float ss = 0.f;
#pragma unroll
    for (int k = 0; k < 9; ++k) {
        int j = tid + k * 256;
        float yv = b2ff(yp[j]);
        float zv = b2ff(zp[j]);
        float g = yv * (zv / (1.f + expf(-zv)));
        vals[k] = g;
        ss = fmaf(g, g, ss);
    }
#pragma unroll
    for (int off = 32; off > 0; off >>= 1) ss += __shfl_xor(ss, off, 64);
    __shared__ float red[4];
    if ((tid & 63) == 0) red[tid >> 6] = ss;
    __syncthreads();
    float tot = red[0] + red[1] + red[2] + red[3];
    float inv = rsqrtf(tot * (1.f / D_INNER) + EPSF);
#pragma unroll
    for (int k = 0; k < 9; ++k) {
        int j = tid + k * 256;
        yp[j] = f2bb(vals[k] * inv * nw[j]);
    }
}

// ---------------------------------------------------------------------------
// GEMM2: out = y_norm @ out_proj_w.T ; M=nb*4096, N=1152, K=2304
// *** FP32 output — d_out is float per the reference's fp32 return ***
// ---------------------------------------------------------------------------
__global__ __launch_bounds__(256) void k_gemm_out(
    const unsigned short* __restrict__ Yn, const float* __restrict__ W,
    float* __restrict__ out)
{
    __shared__ float As[16][64];
    __shared__ float Bs[16][64];
    const int K = D_INNER;
    int tid = threadIdx.x;
    int bm = blockIdx.x, bn = blockIdx.y;
    int tx = tid & 15, ty = tid >> 4;
    int lrow = tid >> 2;
    int lk   = (tid & 3) << 2;
    const unsigned short* aptr = Yn + (size_t)(bm * 64 + lrow) * K + lk;
    const float* bptr = W + (size_t)(bn * 64 + lrow) * K + lk;
    float acc[4][4];
#pragma unroll
    for (int i = 0; i < 4; ++i)
#pragma unroll
        for (int j = 0; j < 4; ++j) acc[i][j] = 0.f;

    for (int k0 = 0; k0 < K; k0 += 16) {
        float4 av = bu4_to_f4(*(const ushort4*)(aptr + k0));
        float4 bv = *(const float4*)(bptr + k0);
        __syncthreads();
        As[lk + 0][lrow] = av.x; As[lk + 1][lrow] = av.y;
        As[lk + 2][lrow] = av.z; As[lk + 3][lrow] = av.w;
        Bs[lk + 0][lrow] = bv.x; Bs[lk + 1][lrow] = bv.y;
        Bs[lk + 2][lrow] = bv.z; Bs[lk + 3][lrow] = bv.w;
        __syncthreads();
#pragma unroll
        for (int kk = 0; kk < 16; ++kk) {
            float4 a4 = *(const float4*)&As[kk][ty << 2];
            float4 b4 = *(const float4*)&Bs[kk][tx << 2];
            float a[4] = {a4.x, a4.y, a4.z, a4.w};
            float b[4] = {b4.x, b4.y, b4.z, b4.w};
#pragma unroll
            for (int i = 0; i < 4; ++i)
#pragma unroll
                for (int j = 0; j < 4; ++j) acc[i][j] = fmaf(a[i], b[j], acc[i][j]);
        }
    }
    int m0 = bm * 64 + (ty << 2);
    int n0 = bn * 64 + (tx << 2);
#pragma unroll
    for (int i = 0; i < 4; ++i)
#pragma unroll
        for (int j = 0; j < 4; ++j)
            out[(size_t)(m0 + i) * HID + n0 + j] = acc[i][j];
}

// ---------------------------------------------------------------------------
extern "C" void kernel_launch(void* const* d_in, const int* in_sizes, int n_in,
                              void* d_out, int out_size, void* d_ws, size_t ws_size,
                              hipStream_t stream)
{
    const float* u          = (const float*)d_in[0];
    const float* in_proj_w  = (const float*)d_in[1];
    const float* conv_w     = (const float*)d_in[2];
    const float* conv_b     = (const float*)d_in[3];
    const float* dt_bias    = (const float*)d_in[4];
    const float* A_log      = (const float*)d_in[5];
    const float* D_param    = (const float*)d_in[6];
    const float* norm_w     = (const float*)d_in[7];
    const float* out_proj_w = (const float*)d_in[8];
    float* out = (float*)d_out;   // fp32 output per reference

    // per-batch slice sizes (bytes)
    const size_t SZ_Z1   = (size_t)SEQLEN * D_INNER * 2;    // 18,874,368
    const size_t SZ_XBC1 = (size_t)SEQLEN * CONV_DIMX * 2;  // 19,922,944 (x2: raw+conv)
    const size_t SZ_DT1  = (size_t)SEQLEN * NHEADS * 4;     //    589,824 (x2: dt+adt)
    const size_t SZ_Y1   = (size_t)SEQLEN * D_INNER * 2;    // 18,874,368
    const size_t SLICE   = SZ_Z1 + 2 * SZ_XBC1 + 2 * SZ_DT1 + SZ_Y1; // 78,774,272

    int nb = 0;
    if      (2 * SLICE <= ws_size) nb = 2;
    else if (1 * SLICE <= ws_size) nb = 1;
    else return;   // diagnostic: clean zero output => ws_size < 78.8 MB

    char* p = (char*)d_ws;
    unsigned short* z        = (unsigned short*)p; p += (size_t)nb * SZ_Z1;
    unsigned short* xbc_raw  = (unsigned short*)p; p += (size_t)nb * SZ_XBC1;
    unsigned short* xbc_conv = (unsigned short*)p; p += (size_t)nb * SZ_XBC1;
    float*          dtp      = (float*)p;          p += (size_t)nb * SZ_DT1;
    float*          adt      = (float*)p;          p += (size_t)nb * SZ_DT1;
    unsigned short* y        = (unsigned short*)p; p += (size_t)nb * SZ_Y1;

    for (int b0 = 0; b0 < BATCH; b0 += nb) {
        const float* u_p = u   + (size_t)b0 * SEQLEN * HID;
        float*     out_p = out + (size_t)b0 * SEQLEN * HID;
        int ndt = nb * SEQLEN * NHEADS;

        k_gemm_inproj<<<dim3(nb * SEQLEN / 64, (D_IN_PROJ + 63) / 64), 256, 0, stream>>>(
            u_p, in_proj_w, z, xbc_raw, dtp);
        k_conv<<<dim3((CONV_DIMX + 255) / 256, SEQLEN, nb), 256, 0, stream>>>(
            xbc_raw, conv_w, conv_b, xbc_conv);
        k_dt<<<(ndt + 255) / 256, 256, 0, stream>>>(dtp, adt, dt_bias, A_log, ndt);
        k_ssm<<<dim3(NHEADS, nb), 256, 0, stream>>>(
            xbc_conv, dtp, adt, D_param, y);
        k_norm<<<nb * SEQLEN, 256, 0, stream>>>(y, z, norm_w);
        k_gemm_out<<<dim3(nb * SEQLEN / 64, HID / 64), 256, 0, stream>>>(
            y, out_proj_w, out_p);
    }
}